// Round 1
// baseline (302.012 us; speedup 1.0000x reference)
//
#include <hip/hip_runtime.h>
#include <hip/hip_bf16.h>

typedef __attribute__((ext_vector_type(8))) short short8;
typedef __attribute__((ext_vector_type(4))) float floatx4;

union BF8 { short8 v; __hip_bfloat16 b[8]; };
union BF4U { ushort4 u; __hip_bfloat16 b[4]; };

__device__ __forceinline__ short8 load8(const __hip_bfloat16* p) {
    return *reinterpret_cast<const short8*>(p);
}

__device__ __forceinline__ void storeC(float* p, float v) { *p = v; }
__device__ __forceinline__ void storeC(__hip_bfloat16* p, float v) { *p = __float2bfloat16(v); }

// ---------------- fp32 -> bf16 cast, 4 elems/thread ----------------
__global__ __launch_bounds__(256) void cast_bf16(const float* __restrict__ src,
                                                 __hip_bfloat16* __restrict__ dst, int n4) {
    int i = blockIdx.x * 256 + threadIdx.x;
    if (i >= n4) return;
    float4 v = reinterpret_cast<const float4*>(src)[i];
    BF4U u;
    u.b[0] = __float2bfloat16(v.x);
    u.b[1] = __float2bfloat16(v.y);
    u.b[2] = __float2bfloat16(v.z);
    u.b[3] = __float2bfloat16(v.w);
    reinterpret_cast<ushort4*>(dst)[i] = u.u;
}

// ---------------- GEMM: C[M,N] = A[M,K] * B^T  (B given as [N,K] row-major) --------
// 128x128 block tile, 4 waves of 64x64 (4x4 MFMA 16x16x32 tiles), BK=32.
// grid.z selects weight/output slice via element strides zsB/zsC.
template <typename OutT>
__global__ __launch_bounds__(256) void gemm_bt(const __hip_bfloat16* __restrict__ A,
                                               const __hip_bfloat16* __restrict__ B0,
                                               OutT* __restrict__ C0,
                                               int N, int Kd,
                                               size_t zsB, size_t zsC) {
    __shared__ __hip_bfloat16 lA[128 * 40];  // pad 32 -> 40 (80B = 20 banks, 2-way only)
    __shared__ __hip_bfloat16 lB[128 * 40];
    const __hip_bfloat16* B = B0 + zsB * blockIdx.z;
    OutT* C = C0 + zsC * blockIdx.z;
    const int t = threadIdx.x;
    const int m0 = blockIdx.x * 128, n0 = blockIdx.y * 128;
    const int w = t >> 6, l = t & 63;
    const int wr = (w >> 1) * 64, wc = (w & 1) * 64;
    const int lr = l & 15, lq = l >> 4;

    const floatx4 zero4 = {0.f, 0.f, 0.f, 0.f};
    floatx4 acc[4][4];
#pragma unroll
    for (int mt = 0; mt < 4; ++mt)
#pragma unroll
        for (int nt = 0; nt < 4; ++nt) acc[mt][nt] = zero4;

    for (int k0 = 0; k0 < Kd; k0 += 32) {
        // stage 128x32 of A and of B: 1024 x 16B loads, 4 per thread
#pragma unroll
        for (int i = 0; i < 4; ++i) {
            int flat = t + i * 256;
            int f = flat & 511;
            int row = f >> 2, ch = f & 3;
            const __hip_bfloat16* src = (flat >= 512)
                ? (B + (size_t)(n0 + row) * Kd + k0 + ch * 8)
                : (A + (size_t)(m0 + row) * Kd + k0 + ch * 8);
            __hip_bfloat16* dst = ((flat >= 512) ? lB : lA) + row * 40 + ch * 8;
            *reinterpret_cast<short8*>(dst) = load8(src);
        }
        __syncthreads();
        short8 af[4], bfr[4];
#pragma unroll
        for (int mt = 0; mt < 4; ++mt)
            af[mt] = load8(lA + (wr + mt * 16 + lr) * 40 + lq * 8);
#pragma unroll
        for (int nt = 0; nt < 4; ++nt)
            bfr[nt] = load8(lB + (wc + nt * 16 + lr) * 40 + lq * 8);
#pragma unroll
        for (int mt = 0; mt < 4; ++mt)
#pragma unroll
            for (int nt = 0; nt < 4; ++nt)
                acc[mt][nt] = __builtin_amdgcn_mfma_f32_16x16x32_bf16(
                    af[mt], bfr[nt], acc[mt][nt], 0, 0, 0);
        __syncthreads();
    }
    // epilogue: C/D layout col=lane&15, row=(lane>>4)*4+reg
#pragma unroll
    for (int mt = 0; mt < 4; ++mt)
#pragma unroll
        for (int nt = 0; nt < 4; ++nt)
#pragma unroll
            for (int r = 0; r < 4; ++r) {
                int row = m0 + wr + mt * 16 + lq * 4 + r;
                int col = n0 + wc + nt * 16 + lr;
                storeC(C + (size_t)row * N + col, acc[mt][nt][r]);
            }
}

// ---------------- per-head L2 normalize (in place), one wave per 64-chunk --------
__global__ __launch_bounds__(256) void norm_heads(__hip_bfloat16* __restrict__ Q,
                                                  __hip_bfloat16* __restrict__ Kt,
                                                  int ngroups) {
    int wid = blockIdx.x * 4 + (threadIdx.x >> 6);
    int l = threadIdx.x & 63;
    __hip_bfloat16* base = (wid < ngroups) ? (Q + (size_t)wid * 64)
                                           : (Kt + (size_t)(wid - ngroups) * 64);
    float x = __bfloat162float(base[l]);
    float s = x * x;
#pragma unroll
    for (int off = 1; off < 64; off <<= 1) s += __shfl_xor(s, off, 64);
    base[l] = __float2bfloat16(x / (sqrtf(s) + 1e-6f));
}

// ---------------- V [B,S,H,hd] -> Vt [B,H,hd,S] ----------------
__global__ __launch_bounds__(256) void transpose_v(const __hip_bfloat16* __restrict__ V,
                                                   __hip_bfloat16* __restrict__ Vt) {
    const int S = 2048, D = 1024;
    __shared__ __hip_bfloat16 tile[64][72];
    int t = threadIdx.x;
    int s0 = blockIdx.x * 64;
    int bh = blockIdx.y, b = bh >> 4, h = bh & 15;
    const __hip_bfloat16* src = V + ((size_t)b * S) * D + h * 64;
#pragma unroll
    for (int i = 0; i < 2; ++i) {
        int flat = t + i * 256;
        int sr = flat >> 3, ch = flat & 7;
        *reinterpret_cast<short8*>(&tile[sr][ch * 8]) =
            load8(src + (size_t)(s0 + sr) * D + ch * 8);
    }
    __syncthreads();
    __hip_bfloat16* dst = Vt + (size_t)bh * 64 * S;
#pragma unroll
    for (int i = 0; i < 2; ++i) {
        int flat = t + i * 256;
        int d = flat >> 3, sc = flat & 7;
        BF8 u;
#pragma unroll
        for (int j = 0; j < 8; ++j) u.b[j] = tile[sc * 8 + j][d];
        *reinterpret_cast<short8*>(dst + (size_t)d * S + s0 + sc * 8) = u.v;
    }
}

// ---------------- causal flash attention, no max-tracking (|score|<=0.125) -------
// 1 wave per block; wave handles 32 q-rows; k-step = 32 cols.
__global__ __launch_bounds__(64) void flash_attn(const __hip_bfloat16* __restrict__ Q,
                                                 const __hip_bfloat16* __restrict__ K,
                                                 const __hip_bfloat16* __restrict__ Vt,
                                                 __hip_bfloat16* __restrict__ O,
                                                 const float* __restrict__ scale_p) {
    const int S = 2048, D = 1024;
    __shared__ __hip_bfloat16 lP[32 * 40];
    const float scale = *scale_p;
    const int l = threadIdx.x;
    const int lr = l & 15, lq = l >> 4;
    const int bh = blockIdx.y, b = bh >> 4, h = bh & 15;
    const int qt = blockIdx.x, q0 = qt * 32;
    const __hip_bfloat16* Qb = Q + ((size_t)b * S) * D + h * 64;
    const __hip_bfloat16* Kb = K + ((size_t)b * S) * D + h * 64;
    const __hip_bfloat16* Vb = Vt + (size_t)bh * 64 * S;

    // Q fragments (A-layout): A[m=lr][k=lq*8+j], kt = which 32-wide K chunk of hd
    short8 aq[2][2];
#pragma unroll
    for (int mt = 0; mt < 2; ++mt)
#pragma unroll
        for (int kt = 0; kt < 2; ++kt)
            aq[mt][kt] = load8(Qb + (size_t)(q0 + mt * 16 + lr) * D + kt * 32 + lq * 8);

    const floatx4 zero4 = {0.f, 0.f, 0.f, 0.f};
    floatx4 oacc[2][4];
    float lsum[2][4];
#pragma unroll
    for (int mt = 0; mt < 2; ++mt) {
#pragma unroll
        for (int nt = 0; nt < 4; ++nt) oacc[mt][nt] = zero4;
#pragma unroll
        for (int r = 0; r < 4; ++r) lsum[mt][r] = 0.f;
    }

    for (int ks = 0; ks <= qt; ++ks) {
        const int k0 = ks * 32;
        // S = Q K^T : B^T layout fragments straight from K rows
        short8 bk[2][2];
#pragma unroll
        for (int nt = 0; nt < 2; ++nt)
#pragma unroll
            for (int kt = 0; kt < 2; ++kt)
                bk[nt][kt] = load8(Kb + (size_t)(k0 + nt * 16 + lr) * D + kt * 32 + lq * 8);
        floatx4 sacc[2][2];
#pragma unroll
        for (int mt = 0; mt < 2; ++mt)
#pragma unroll
            for (int nt = 0; nt < 2; ++nt) sacc[mt][nt] = zero4;
#pragma unroll
        for (int mt = 0; mt < 2; ++mt)
#pragma unroll
            for (int nt = 0; nt < 2; ++nt)
#pragma unroll
                for (int kt = 0; kt < 2; ++kt)
                    sacc[mt][nt] = __builtin_amdgcn_mfma_f32_16x16x32_bf16(
                        aq[mt][kt], bk[nt][kt], sacc[mt][nt], 0, 0, 0);
        // P = exp(s*scale) with causal mask; stash into LDS (C-layout), track row sums
#pragma unroll
        for (int mt = 0; mt < 2; ++mt)
#pragma unroll
            for (int nt = 0; nt < 2; ++nt)
#pragma unroll
                for (int r = 0; r < 4; ++r) {
                    int qg = q0 + mt * 16 + lq * 4 + r;
                    int kg = k0 + nt * 16 + lr;
                    float p = (kg <= qg) ? __expf(sacc[mt][nt][r] * scale) : 0.f;
                    __hip_bfloat16 pb = __float2bfloat16(p);
                    lsum[mt][r] += __bfloat162float(pb);  // consistent with PV operand
                    lP[(mt * 16 + lq * 4 + r) * 40 + nt * 16 + lr] = pb;
                }
        __syncthreads();  // single wave: cheap; orders LDS write->read
        short8 ap[2];
#pragma unroll
        for (int mt = 0; mt < 2; ++mt)
            ap[mt] = load8(&lP[(mt * 16 + lr) * 40 + lq * 8]);
        short8 bv[4];
#pragma unroll
        for (int nt = 0; nt < 4; ++nt)
            bv[nt] = load8(Vb + (size_t)(nt * 16 + lr) * S + k0 + lq * 8);
#pragma unroll
        for (int mt = 0; mt < 2; ++mt)
#pragma unroll
            for (int nt = 0; nt < 4; ++nt)
                oacc[mt][nt] = __builtin_amdgcn_mfma_f32_16x16x32_bf16(
                    ap[mt], bv[nt], oacc[mt][nt], 0, 0, 0);
        __syncthreads();  // protect lP before next iter's writes
    }

    // reduce row sums across the 16 col-lanes (xor of bits 0..3 stays in-group)
#pragma unroll
    for (int mt = 0; mt < 2; ++mt)
#pragma unroll
        for (int r = 0; r < 4; ++r) {
            float s = lsum[mt][r];
            s += __shfl_xor(s, 1, 64);
            s += __shfl_xor(s, 2, 64);
            s += __shfl_xor(s, 4, 64);
            s += __shfl_xor(s, 8, 64);
            lsum[mt][r] = s;
        }

    __hip_bfloat16* Ob = O + ((size_t)b * S) * D + h * 64;
#pragma unroll
    for (int mt = 0; mt < 2; ++mt)
#pragma unroll
        for (int nt = 0; nt < 4; ++nt)
#pragma unroll
            for (int r = 0; r < 4; ++r) {
                int row = q0 + mt * 16 + lq * 4 + r;
                int col = nt * 16 + lr;
                Ob[(size_t)row * D + col] =
                    __float2bfloat16(oacc[mt][nt][r] / lsum[mt][r]);
            }
}

extern "C" void kernel_launch(void* const* d_in, const int* in_sizes, int n_in,
                              void* d_out, int out_size, void* d_ws, size_t ws_size,
                              hipStream_t stream) {
    const float* hs  = (const float*)d_in[0];  // [2,2048,1024]
    const float* wq  = (const float*)d_in[1];  // [1024,1024]
    const float* wk  = (const float*)d_in[2];
    const float* wv  = (const float*)d_in[3];
    const float* wo  = (const float*)d_in[4];
    const float* qkf = (const float*)d_in[5];  // scalar

    char* ws = (char*)d_ws;
    const size_t MB = 1024 * 1024;
    __hip_bfloat16* Xb  = (__hip_bfloat16*)(ws);            // 8 MB  [4096,1024]
    __hip_bfloat16* Wqb = (__hip_bfloat16*)(ws + 8 * MB);   // 2 MB each, contiguous
    __hip_bfloat16* Wob = (__hip_bfloat16*)(ws + 14 * MB);
    __hip_bfloat16* Qb  = (__hip_bfloat16*)(ws + 16 * MB);  // 8 MB each, contiguous
    __hip_bfloat16* Kb  = (__hip_bfloat16*)(ws + 24 * MB);
    __hip_bfloat16* Vb  = (__hip_bfloat16*)(ws + 32 * MB);
    __hip_bfloat16* Vt  = (__hip_bfloat16*)(ws + 40 * MB);  // 8 MB [B,H,64,2048]
    __hip_bfloat16* Ab  = (__hip_bfloat16*)(ws + 48 * MB);  // 8 MB attn out

    cast_bf16<<<4096, 256, 0, stream>>>(hs, Xb, 1048576);
    cast_bf16<<<1024, 256, 0, stream>>>(wq, Wqb, 262144);
    cast_bf16<<<1024, 256, 0, stream>>>(wk, (__hip_bfloat16*)(ws + 10 * MB), 262144);
    cast_bf16<<<1024, 256, 0, stream>>>(wv, (__hip_bfloat16*)(ws + 12 * MB), 262144);
    cast_bf16<<<1024, 256, 0, stream>>>(wo, Wob, 262144);

    // Q,K,V projections in one launch: z selects W (stride 1M elems) and C (stride 4M elems)
    gemm_bt<__hip_bfloat16><<<dim3(32, 8, 3), 256, 0, stream>>>(
        Xb, Wqb, Qb, 1024, 1024, (size_t)1048576, (size_t)4194304);

    norm_heads<<<32768, 256, 0, stream>>>(Qb, Kb, 65536);
    transpose_v<<<dim3(32, 32), 256, 0, stream>>>(Vb, Vt);
    flash_attn<<<dim3(64, 32), 64, 0, stream>>>(Qb, Kb, Vt, Ab, qkf);

    gemm_bt<float><<<dim3(32, 8, 1), 256, 0, stream>>>(
        Ab, Wob, (float*)d_out, 1024, 1024, (size_t)0, (size_t)0);
}

// Round 2
// 274.570 us; speedup vs baseline: 1.0999x; 1.0999x over previous
//
#include <hip/hip_runtime.h>
#include <hip/hip_bf16.h>

typedef __attribute__((ext_vector_type(8))) short short8;
typedef __attribute__((ext_vector_type(4))) float floatx4;

union BF8 { short8 v; __hip_bfloat16 b[8]; };
union BF4U { ushort4 u; __hip_bfloat16 b[4]; };

__device__ __forceinline__ short8 load8(const __hip_bfloat16* p) {
    return *reinterpret_cast<const short8*>(p);
}

__device__ __forceinline__ void storeC(float* p, float v) { *p = v; }
__device__ __forceinline__ void storeC(__hip_bfloat16* p, float v) { *p = __float2bfloat16(v); }

// async global->LDS, 16B per lane. LDS dest must be wave-uniform base + lane*16.
__device__ __forceinline__ void gload_lds16(const __hip_bfloat16* g, __hip_bfloat16* l) {
    __builtin_amdgcn_global_load_lds(
        (const __attribute__((address_space(1))) void*)g,
        (__attribute__((address_space(3))) void*)l, 16, 0, 0);
}

// ---------------- fp32 -> bf16 cast, 4 elems/thread ----------------
__global__ __launch_bounds__(256) void cast_bf16(const float* __restrict__ src,
                                                 __hip_bfloat16* __restrict__ dst, int n4) {
    int i = blockIdx.x * 256 + threadIdx.x;
    if (i >= n4) return;
    float4 v = reinterpret_cast<const float4*>(src)[i];
    BF4U u;
    u.b[0] = __float2bfloat16(v.x);
    u.b[1] = __float2bfloat16(v.y);
    u.b[2] = __float2bfloat16(v.z);
    u.b[3] = __float2bfloat16(v.w);
    reinterpret_cast<ushort4*>(dst)[i] = u.u;
}

// 4 weight matrices (each 1M elems) -> contiguous bf16 slices of 1M elems
__global__ __launch_bounds__(256) void cast4_bf16(const float* __restrict__ a,
                                                  const float* __restrict__ b,
                                                  const float* __restrict__ c,
                                                  const float* __restrict__ d,
                                                  __hip_bfloat16* __restrict__ dst) {
    int y = blockIdx.y;
    const float* src = (y == 0) ? a : (y == 1) ? b : (y == 2) ? c : d;
    int i = blockIdx.x * 256 + threadIdx.x;  // grid.x = 1024 -> 262144 float4s
    float4 v = reinterpret_cast<const float4*>(src)[i];
    BF4U u;
    u.b[0] = __float2bfloat16(v.x);
    u.b[1] = __float2bfloat16(v.y);
    u.b[2] = __float2bfloat16(v.z);
    u.b[3] = __float2bfloat16(v.w);
    reinterpret_cast<ushort4*>(dst + (size_t)y * 1048576)[i] = u.u;
}

// ---------------- GEMM: C[M,N] = A[M,K] * B^T  (B given as [N,K] row-major) --------
// m97 structure: 128x128 tile, BK=32, global_load_lds width=16 into UNPADDED LDS.
template <typename OutT>
__global__ __launch_bounds__(256) void gemm_bt(const __hip_bfloat16* __restrict__ A,
                                               const __hip_bfloat16* __restrict__ B0,
                                               OutT* __restrict__ C0,
                                               int N, int Kd,
                                               size_t zsB, size_t zsC) {
    __shared__ __hip_bfloat16 lA[128 * 32];  // unpadded: row*64B + ch*16B == flat*16B
    __shared__ __hip_bfloat16 lB[128 * 32];
    const __hip_bfloat16* B = B0 + zsB * blockIdx.z;
    OutT* C = C0 + zsC * blockIdx.z;
    const int t = threadIdx.x;
    const int m0 = blockIdx.x * 128, n0 = blockIdx.y * 128;
    const int w = t >> 6, l = t & 63;
    const int wr = (w >> 1) * 64, wc = (w & 1) * 64;
    const int lr = l & 15, lq = l >> 4;

    const floatx4 zero4 = {0.f, 0.f, 0.f, 0.f};
    floatx4 acc[4][4];
#pragma unroll
    for (int mt = 0; mt < 4; ++mt)
#pragma unroll
        for (int nt = 0; nt < 4; ++nt) acc[mt][nt] = zero4;

    for (int k0 = 0; k0 < Kd; k0 += 32) {
#pragma unroll
        for (int i = 0; i < 2; ++i) {
            int flat = t + i * 256;          // 0..511
            int row = flat >> 2, ch = flat & 3;
            gload_lds16(A + (size_t)(m0 + row) * Kd + k0 + ch * 8, lA + flat * 8);
            gload_lds16(B + (size_t)(n0 + row) * Kd + k0 + ch * 8, lB + flat * 8);
        }
        __syncthreads();  // drains vmcnt: staging complete
        short8 af[4], bfr[4];
#pragma unroll
        for (int mt = 0; mt < 4; ++mt)
            af[mt] = load8(lA + (wr + mt * 16 + lr) * 32 + lq * 8);
#pragma unroll
        for (int nt = 0; nt < 4; ++nt)
            bfr[nt] = load8(lB + (wc + nt * 16 + lr) * 32 + lq * 8);
#pragma unroll
        for (int mt = 0; mt < 4; ++mt)
#pragma unroll
            for (int nt = 0; nt < 4; ++nt)
                acc[mt][nt] = __builtin_amdgcn_mfma_f32_16x16x32_bf16(
                    af[mt], bfr[nt], acc[mt][nt], 0, 0, 0);
        __syncthreads();
    }
#pragma unroll
    for (int mt = 0; mt < 4; ++mt)
#pragma unroll
        for (int nt = 0; nt < 4; ++nt)
#pragma unroll
            for (int r = 0; r < 4; ++r) {
                int row = m0 + wr + mt * 16 + lq * 4 + r;
                int col = n0 + wc + nt * 16 + lr;
                storeC(C + (size_t)row * N + col, acc[mt][nt][r]);
            }
}

// ---------------- per-head L2 normalize (in place), one wave per 64-chunk --------
__global__ __launch_bounds__(256) void norm_heads(__hip_bfloat16* __restrict__ Q,
                                                  __hip_bfloat16* __restrict__ Kt,
                                                  int ngroups) {
    int wid = blockIdx.x * 4 + (threadIdx.x >> 6);
    int l = threadIdx.x & 63;
    __hip_bfloat16* base = (wid < ngroups) ? (Q + (size_t)wid * 64)
                                           : (Kt + (size_t)(wid - ngroups) * 64);
    float x = __bfloat162float(base[l]);
    float s = x * x;
#pragma unroll
    for (int off = 1; off < 64; off <<= 1) s += __shfl_xor(s, off, 64);
    base[l] = __float2bfloat16(x / (sqrtf(s) + 1e-6f));
}

// ---------------- V [B,S,H,hd] -> Vt [B,H,hd,S] ----------------
__global__ __launch_bounds__(256) void transpose_v(const __hip_bfloat16* __restrict__ V,
                                                   __hip_bfloat16* __restrict__ Vt) {
    const int S = 2048, D = 1024;
    __shared__ __hip_bfloat16 tile[64][72];
    int t = threadIdx.x;
    int s0 = blockIdx.x * 64;
    int bh = blockIdx.y, b = bh >> 4, h = bh & 15;
    const __hip_bfloat16* src = V + ((size_t)b * S) * D + h * 64;
#pragma unroll
    for (int i = 0; i < 2; ++i) {
        int flat = t + i * 256;
        int sr = flat >> 3, ch = flat & 7;
        *reinterpret_cast<short8*>(&tile[sr][ch * 8]) =
            load8(src + (size_t)(s0 + sr) * D + ch * 8);
    }
    __syncthreads();
    __hip_bfloat16* dst = Vt + (size_t)bh * 64 * S;
#pragma unroll
    for (int i = 0; i < 2; ++i) {
        int flat = t + i * 256;
        int d = flat >> 3, sc = flat & 7;
        BF8 u;
#pragma unroll
        for (int j = 0; j < 8; ++j) u.b[j] = tile[sc * 8 + j][d];
        *reinterpret_cast<short8*>(dst + (size_t)d * S + s0 + sc * 8) = u.v;
    }
}

// ---------------- causal flash attention, k-split across 4 waves -----------------
// No max-tracking (|score| <= 0.125): O = sum_k P*V and l = sum_k P are associative,
// so wave w handles ks = w, w+4, ... independently; cross-wave fp32 reduce at end.
// No __syncthreads in the k-loop: each wave has a PRIVATE LDS P-buffer; in-wave
// write->read ordering enforced by explicit s_waitcnt lgkmcnt(0).
__global__ __launch_bounds__(256) void flash_attn(const __hip_bfloat16* __restrict__ Q,
                                                  const __hip_bfloat16* __restrict__ K,
                                                  const __hip_bfloat16* __restrict__ Vt,
                                                  __hip_bfloat16* __restrict__ O,
                                                  const float* __restrict__ scale_p) {
    const int S = 2048, D = 1024;
    // phase 1: lP = 4 waves x 32x40 bf16 (10240 B, per-wave private)
    // phase 2 (after the single barrier): oP = 4 x 32x68 fp32 (34816 B) + lsum 4x32 fp32
    __shared__ __align__(16) char smem[35328];
    const float scale = *scale_p;
    const int t = threadIdx.x;
    const int w = t >> 6, l = t & 63;
    const int lr = l & 15, lq = l >> 4;
    const int bh = blockIdx.y, b = bh >> 4, h = bh & 15;
    const int qt = gridDim.x - 1 - blockIdx.x;  // long blocks first
    const int q0 = qt * 32;
    const __hip_bfloat16* Qb = Q + ((size_t)b * S) * D + h * 64;
    const __hip_bfloat16* Kb = K + ((size_t)b * S) * D + h * 64;
    const __hip_bfloat16* Vb = Vt + (size_t)bh * 64 * S;
    __hip_bfloat16* lPw = reinterpret_cast<__hip_bfloat16*>(smem) + w * (32 * 40);

    short8 aq[2][2];
#pragma unroll
    for (int mt = 0; mt < 2; ++mt)
#pragma unroll
        for (int kt = 0; kt < 2; ++kt)
            aq[mt][kt] = load8(Qb + (size_t)(q0 + mt * 16 + lr) * D + kt * 32 + lq * 8);

    const floatx4 zero4 = {0.f, 0.f, 0.f, 0.f};
    floatx4 oacc[2][4];
    float lsum[2][4];
#pragma unroll
    for (int mt = 0; mt < 2; ++mt) {
#pragma unroll
        for (int nt = 0; nt < 4; ++nt) oacc[mt][nt] = zero4;
#pragma unroll
        for (int r = 0; r < 4; ++r) lsum[mt][r] = 0.f;
    }

    for (int ks = w; ks <= qt; ks += 4) {
        const int k0 = ks * 32;
        short8 bk[2][2];
#pragma unroll
        for (int nt = 0; nt < 2; ++nt)
#pragma unroll
            for (int kt = 0; kt < 2; ++kt)
                bk[nt][kt] = load8(Kb + (size_t)(k0 + nt * 16 + lr) * D + kt * 32 + lq * 8);
        floatx4 sacc[2][2];
#pragma unroll
        for (int mt = 0; mt < 2; ++mt)
#pragma unroll
            for (int nt = 0; nt < 2; ++nt) sacc[mt][nt] = zero4;
#pragma unroll
        for (int mt = 0; mt < 2; ++mt)
#pragma unroll
            for (int nt = 0; nt < 2; ++nt)
#pragma unroll
                for (int kt = 0; kt < 2; ++kt)
                    sacc[mt][nt] = __builtin_amdgcn_mfma_f32_16x16x32_bf16(
                        aq[mt][kt], bk[nt][kt], sacc[mt][nt], 0, 0, 0);
        // P = exp(s*scale), causal-masked; C-layout -> private LDS; track row sums
#pragma unroll
        for (int mt = 0; mt < 2; ++mt)
#pragma unroll
            for (int nt = 0; nt < 2; ++nt)
#pragma unroll
                for (int r = 0; r < 4; ++r) {
                    int qg = q0 + mt * 16 + lq * 4 + r;
                    int kg = k0 + nt * 16 + lr;
                    float p = (kg <= qg) ? __expf(sacc[mt][nt][r] * scale) : 0.f;
                    __hip_bfloat16 pb = __float2bfloat16(p);
                    lsum[mt][r] += __bfloat162float(pb);
                    lPw[(mt * 16 + lq * 4 + r) * 40 + nt * 16 + lr] = pb;
                }
        // in-wave LDS RAW fence (private region; no cross-wave barrier needed)
        asm volatile("s_waitcnt lgkmcnt(0)" ::: "memory");
        short8 ap[2];
#pragma unroll
        for (int mt = 0; mt < 2; ++mt)
            ap[mt] = load8(lPw + (mt * 16 + lr) * 40 + lq * 8);
        short8 bv[4];
#pragma unroll
        for (int nt = 0; nt < 4; ++nt)
            bv[nt] = load8(Vb + (size_t)(nt * 16 + lr) * S + k0 + lq * 8);
#pragma unroll
        for (int mt = 0; mt < 2; ++mt)
#pragma unroll
            for (int nt = 0; nt < 4; ++nt)
                oacc[mt][nt] = __builtin_amdgcn_mfma_f32_16x16x32_bf16(
                    ap[mt], bv[nt], oacc[mt][nt], 0, 0, 0);
    }

    // reduce row sums across the 16 col-lanes (within each lq group)
#pragma unroll
    for (int mt = 0; mt < 2; ++mt)
#pragma unroll
        for (int r = 0; r < 4; ++r) {
            float s = lsum[mt][r];
            s += __shfl_xor(s, 1, 64);
            s += __shfl_xor(s, 2, 64);
            s += __shfl_xor(s, 4, 64);
            s += __shfl_xor(s, 8, 64);
            lsum[mt][r] = s;
        }

    __syncthreads();  // all waves done with lP; repurpose LDS for partial-O reduce

    float* oPw = reinterpret_cast<float*>(smem) + w * (32 * 68);
    float* lsumL = reinterpret_cast<float*>(smem + 34816);
#pragma unroll
    for (int mt = 0; mt < 2; ++mt)
#pragma unroll
        for (int nt = 0; nt < 4; ++nt)
#pragma unroll
            for (int r = 0; r < 4; ++r)
                oPw[(mt * 16 + lq * 4 + r) * 68 + nt * 16 + lr] = oacc[mt][nt][r];
    if (lr == 0) {
#pragma unroll
        for (int mt = 0; mt < 2; ++mt)
#pragma unroll
            for (int r = 0; r < 4; ++r)
                lsumL[w * 32 + mt * 16 + lq * 4 + r] = lsum[mt][r];
    }
    __syncthreads();

    // combine 4 wave-partials: thread -> (row = t>>3, cols (t&7)*8 .. +7)
    const int row = t >> 3, c0 = (t & 7) * 8;
    const float* oP = reinterpret_cast<const float*>(smem);
    float Ltot = lsumL[row] + lsumL[32 + row] + lsumL[64 + row] + lsumL[96 + row];
    float inv = 1.f / Ltot;
    float4 a0 = {0.f, 0.f, 0.f, 0.f}, a1 = {0.f, 0.f, 0.f, 0.f};
#pragma unroll
    for (int w2 = 0; w2 < 4; ++w2) {
        const float4* p = reinterpret_cast<const float4*>(oP + w2 * (32 * 68) + row * 68 + c0);
        float4 v0 = p[0], v1 = p[1];
        a0.x += v0.x; a0.y += v0.y; a0.z += v0.z; a0.w += v0.w;
        a1.x += v1.x; a1.y += v1.y; a1.z += v1.z; a1.w += v1.w;
    }
    BF8 u;
    u.b[0] = __float2bfloat16(a0.x * inv);
    u.b[1] = __float2bfloat16(a0.y * inv);
    u.b[2] = __float2bfloat16(a0.z * inv);
    u.b[3] = __float2bfloat16(a0.w * inv);
    u.b[4] = __float2bfloat16(a1.x * inv);
    u.b[5] = __float2bfloat16(a1.y * inv);
    u.b[6] = __float2bfloat16(a1.z * inv);
    u.b[7] = __float2bfloat16(a1.w * inv);
    __hip_bfloat16* Ob = O + ((size_t)b * S) * D + h * 64;
    *reinterpret_cast<short8*>(Ob + (size_t)(q0 + row) * D + c0) = u.v;
}

extern "C" void kernel_launch(void* const* d_in, const int* in_sizes, int n_in,
                              void* d_out, int out_size, void* d_ws, size_t ws_size,
                              hipStream_t stream) {
    const float* hs  = (const float*)d_in[0];  // [2,2048,1024]
    const float* wq  = (const float*)d_in[1];  // [1024,1024]
    const float* wk  = (const float*)d_in[2];
    const float* wv  = (const float*)d_in[3];
    const float* wo  = (const float*)d_in[4];
    const float* qkf = (const float*)d_in[5];  // scalar

    char* ws = (char*)d_ws;
    const size_t MB = 1024 * 1024;
    __hip_bfloat16* Xb  = (__hip_bfloat16*)(ws);            // 8 MB  [4096,1024]
    __hip_bfloat16* Wqb = (__hip_bfloat16*)(ws + 8 * MB);   // 2 MB each: Wq,Wk,Wv,Wo
    __hip_bfloat16* Wob = (__hip_bfloat16*)(ws + 14 * MB);
    __hip_bfloat16* Qb  = (__hip_bfloat16*)(ws + 16 * MB);  // 8 MB each, contiguous
    __hip_bfloat16* Kb  = (__hip_bfloat16*)(ws + 24 * MB);
    __hip_bfloat16* Vb  = (__hip_bfloat16*)(ws + 32 * MB);
    __hip_bfloat16* Vt  = (__hip_bfloat16*)(ws + 40 * MB);  // 8 MB [B,H,64,2048]
    __hip_bfloat16* Ab  = (__hip_bfloat16*)(ws + 48 * MB);  // 8 MB attn out

    cast_bf16<<<4096, 256, 0, stream>>>(hs, Xb, 1048576);
    cast4_bf16<<<dim3(1024, 4), 256, 0, stream>>>(wq, wk, wv, wo, Wqb);

    // Q,K,V projections: z selects W (stride 1M elems) and C (stride 4M elems)
    gemm_bt<__hip_bfloat16><<<dim3(32, 8, 3), 256, 0, stream>>>(
        Xb, Wqb, Qb, 1024, 1024, (size_t)1048576, (size_t)4194304);

    norm_heads<<<32768, 256, 0, stream>>>(Qb, Kb, 65536);
    transpose_v<<<dim3(32, 32), 256, 0, stream>>>(Vb, Vt);
    flash_attn<<<dim3(64, 32), 256, 0, stream>>>(Qb, Kb, Vt, Ab, qkf);

    gemm_bt<float><<<dim3(32, 8, 1), 256, 0, stream>>>(
        Ab, Wob, (float*)d_out, 1024, 1024, (size_t)0, (size_t)0);
}

// Round 3
// 238.709 us; speedup vs baseline: 1.2652x; 1.1502x over previous
//
#include <hip/hip_runtime.h>
#include <hip/hip_bf16.h>

typedef __attribute__((ext_vector_type(8))) short short8;
typedef __attribute__((ext_vector_type(4))) float floatx4;

union BF8 { short8 v; __hip_bfloat16 b[8]; };
union BF4U { ushort4 u; __hip_bfloat16 b[4]; };

__device__ __forceinline__ short8 load8(const __hip_bfloat16* p) {
    return *reinterpret_cast<const short8*>(p);
}

__device__ __forceinline__ void storeC(float* p, float v) { *p = v; }
__device__ __forceinline__ void storeC(__hip_bfloat16* p, float v) { *p = __float2bfloat16(v); }

// pack two fp32 -> two bf16 (round-half-up) in one dword: [lo]=a, [hi]=b
__device__ __forceinline__ unsigned pack_bf16(float a, float b) {
    unsigned ua = __float_as_uint(a) + 0x8000u;
    unsigned ub = __float_as_uint(b) + 0x8000u;
    return __builtin_amdgcn_perm(ub, ua, 0x07060302u);  // D.b01=ua.b23, D.b23=ub.b23
}

// async global->LDS, 16B per lane. LDS dest must be wave-uniform base + lane*16.
__device__ __forceinline__ void gload_lds16(const __hip_bfloat16* g, __hip_bfloat16* l) {
    __builtin_amdgcn_global_load_lds(
        (const __attribute__((address_space(1))) void*)g,
        (__attribute__((address_space(3))) void*)l, 16, 0, 0);
}

// ---------------- fp32 -> bf16 cast, 4 elems/thread ----------------
__global__ __launch_bounds__(256) void cast_bf16(const float* __restrict__ src,
                                                 __hip_bfloat16* __restrict__ dst, int n4) {
    int i = blockIdx.x * 256 + threadIdx.x;
    if (i >= n4) return;
    float4 v = reinterpret_cast<const float4*>(src)[i];
    BF4U u;
    u.b[0] = __float2bfloat16(v.x);
    u.b[1] = __float2bfloat16(v.y);
    u.b[2] = __float2bfloat16(v.z);
    u.b[3] = __float2bfloat16(v.w);
    reinterpret_cast<ushort4*>(dst)[i] = u.u;
}

// 4 weight matrices (each 1M elems) -> contiguous bf16 slices of 1M elems
__global__ __launch_bounds__(256) void cast4_bf16(const float* __restrict__ a,
                                                  const float* __restrict__ b,
                                                  const float* __restrict__ c,
                                                  const float* __restrict__ d,
                                                  __hip_bfloat16* __restrict__ dst) {
    int y = blockIdx.y;
    const float* src = (y == 0) ? a : (y == 1) ? b : (y == 2) ? c : d;
    int i = blockIdx.x * 256 + threadIdx.x;
    float4 v = reinterpret_cast<const float4*>(src)[i];
    BF4U u;
    u.b[0] = __float2bfloat16(v.x);
    u.b[1] = __float2bfloat16(v.y);
    u.b[2] = __float2bfloat16(v.z);
    u.b[3] = __float2bfloat16(v.w);
    reinterpret_cast<ushort4*>(dst + (size_t)y * 1048576)[i] = u.u;
}

// ---------------- GEMM: C[M,N] = A[M,K] * B^T  (B given as [N,K] row-major) --------
template <typename OutT>
__global__ __launch_bounds__(256) void gemm_bt(const __hip_bfloat16* __restrict__ A,
                                               const __hip_bfloat16* __restrict__ B0,
                                               OutT* __restrict__ C0,
                                               int N, int Kd,
                                               size_t zsB, size_t zsC) {
    __shared__ __hip_bfloat16 lA[128 * 32];
    __shared__ __hip_bfloat16 lB[128 * 32];
    const __hip_bfloat16* B = B0 + zsB * blockIdx.z;
    OutT* C = C0 + zsC * blockIdx.z;
    const int t = threadIdx.x;
    const int m0 = blockIdx.x * 128, n0 = blockIdx.y * 128;
    const int w = t >> 6, l = t & 63;
    const int wr = (w >> 1) * 64, wc = (w & 1) * 64;
    const int lr = l & 15, lq = l >> 4;

    const floatx4 zero4 = {0.f, 0.f, 0.f, 0.f};
    floatx4 acc[4][4];
#pragma unroll
    for (int mt = 0; mt < 4; ++mt)
#pragma unroll
        for (int nt = 0; nt < 4; ++nt) acc[mt][nt] = zero4;

    for (int k0 = 0; k0 < Kd; k0 += 32) {
#pragma unroll
        for (int i = 0; i < 2; ++i) {
            int flat = t + i * 256;
            int row = flat >> 2, ch = flat & 3;
            gload_lds16(A + (size_t)(m0 + row) * Kd + k0 + ch * 8, lA + flat * 8);
            gload_lds16(B + (size_t)(n0 + row) * Kd + k0 + ch * 8, lB + flat * 8);
        }
        __syncthreads();
        short8 af[4], bfr[4];
#pragma unroll
        for (int mt = 0; mt < 4; ++mt)
            af[mt] = load8(lA + (wr + mt * 16 + lr) * 32 + lq * 8);
#pragma unroll
        for (int nt = 0; nt < 4; ++nt)
            bfr[nt] = load8(lB + (wc + nt * 16 + lr) * 32 + lq * 8);
#pragma unroll
        for (int mt = 0; mt < 4; ++mt)
#pragma unroll
            for (int nt = 0; nt < 4; ++nt)
                acc[mt][nt] = __builtin_amdgcn_mfma_f32_16x16x32_bf16(
                    af[mt], bfr[nt], acc[mt][nt], 0, 0, 0);
        __syncthreads();
    }
#pragma unroll
    for (int mt = 0; mt < 4; ++mt)
#pragma unroll
        for (int nt = 0; nt < 4; ++nt)
#pragma unroll
            for (int r = 0; r < 4; ++r) {
                int row = m0 + wr + mt * 16 + lq * 4 + r;
                int col = n0 + wc + nt * 16 + lr;
                storeC(C + (size_t)row * N + col, acc[mt][nt][r]);
            }
}

// ------- per-head L2 normalize (in place); Q additionally scaled by qk factor -----
__global__ __launch_bounds__(256) void norm_heads(__hip_bfloat16* __restrict__ Q,
                                                  __hip_bfloat16* __restrict__ Kt,
                                                  int ngroups,
                                                  const float* __restrict__ scale_p) {
    int wid = blockIdx.x * 4 + (threadIdx.x >> 6);
    int l = threadIdx.x & 63;
    bool isQ = wid < ngroups;
    __hip_bfloat16* base = isQ ? (Q + (size_t)wid * 64)
                               : (Kt + (size_t)(wid - ngroups) * 64);
    float x = __bfloat162float(base[l]);
    float s = x * x;
#pragma unroll
    for (int off = 1; off < 64; off <<= 1) s += __shfl_xor(s, off, 64);
    float v = x / (sqrtf(s) + 1e-6f);
    if (isQ) v *= *scale_p;  // fold qk_norm_factor into normalized Q
    base[l] = __float2bfloat16(v);
}

// ---------------- V [B,S,H,hd] -> Vt [B,H,hd,S] ----------------
__global__ __launch_bounds__(256) void transpose_v(const __hip_bfloat16* __restrict__ V,
                                                   __hip_bfloat16* __restrict__ Vt) {
    const int S = 2048, D = 1024;
    __shared__ __hip_bfloat16 tile[64][72];
    int t = threadIdx.x;
    int s0 = blockIdx.x * 64;
    int bh = blockIdx.y, b = bh >> 4, h = bh & 15;
    const __hip_bfloat16* src = V + ((size_t)b * S) * D + h * 64;
#pragma unroll
    for (int i = 0; i < 2; ++i) {
        int flat = t + i * 256;
        int sr = flat >> 3, ch = flat & 7;
        *reinterpret_cast<short8*>(&tile[sr][ch * 8]) =
            load8(src + (size_t)(s0 + sr) * D + ch * 8);
    }
    __syncthreads();
    __hip_bfloat16* dst = Vt + (size_t)bh * 64 * S;
#pragma unroll
    for (int i = 0; i < 2; ++i) {
        int flat = t + i * 256;
        int d = flat >> 3, sc = flat & 7;
        BF8 u;
#pragma unroll
        for (int j = 0; j < 8; ++j) u.b[j] = tile[sc * 8 + j][d];
        *reinterpret_cast<short8*>(dst + (size_t)d * S + s0 + sc * 8) = u.v;
    }
}

// ---------------- causal flash attention, k-split across 4 waves -----------------
// Computes S^T = K.Q^T so the P-tile exits MFMA with 4 k-consecutive values per
// lane -> pack + ds_write_b64. Row sums via MFMA against a ones B-operand.
// XCD-clustered grid: all 64 q-blocks of a (b,h) land on one XCD's L2.
__global__ __launch_bounds__(256) void flash_attn(const __hip_bfloat16* __restrict__ Q,
                                                  const __hip_bfloat16* __restrict__ K,
                                                  const __hip_bfloat16* __restrict__ Vt,
                                                  __hip_bfloat16* __restrict__ O) {
    const int S = 2048, D = 1024;
    // phase 1: 4 waves x (32 x 40) bf16 P-tiles = 10240 B (per-wave private)
    // phase 2: 4 waves x (32 x 36) fp32 partials = 18432 B (after barrier)
    __shared__ __align__(16) char smem[18432];
    const int t = threadIdx.x;
    const int w = t >> 6, l = t & 63;
    const int lr = l & 15, lq = l >> 4;
    const int id = blockIdx.x, j = id >> 3;
    const int bh = (id & 7) * 4 + (j & 3);     // 4 heads per XCD (id%8 ~ XCD)
    const int qt = 63 - (j >> 2);              // long blocks first
    const int b = bh >> 4, h = bh & 15;
    const int q0 = qt * 32;
    const __hip_bfloat16* Qb = Q + ((size_t)b * S) * D + h * 64;
    const __hip_bfloat16* Kb = K + ((size_t)b * S) * D + h * 64;
    const __hip_bfloat16* Vb = Vt + (size_t)bh * 64 * S;
    __hip_bfloat16* lPw = reinterpret_cast<__hip_bfloat16*>(smem) + w * (32 * 40);

    // Q fragments as B-operand: B[k=lq*8+j][n=lr] = Q[q0+nt*16+lr][kt*32+lq*8+j]
    short8 bq[2][2];
#pragma unroll
    for (int nt = 0; nt < 2; ++nt)
#pragma unroll
        for (int kt = 0; kt < 2; ++kt)
            bq[nt][kt] = load8(Qb + (size_t)(q0 + nt * 16 + lr) * D + kt * 32 + lq * 8);

    const floatx4 zero4 = {0.f, 0.f, 0.f, 0.f};
    floatx4 oacc[2][4], osum[2];
#pragma unroll
    for (int mt = 0; mt < 2; ++mt) {
#pragma unroll
        for (int nt = 0; nt < 4; ++nt) oacc[mt][nt] = zero4;
        osum[mt] = zero4;
    }
    const short ONE = 0x3F80;  // bf16 1.0
    const short8 ones = {ONE, ONE, ONE, ONE, ONE, ONE, ONE, ONE};

    if (w <= qt) {
        short8 bk[2][2], bv[4];
        {
            const int k0 = w * 32;
#pragma unroll
            for (int mt = 0; mt < 2; ++mt)
#pragma unroll
                for (int kt = 0; kt < 2; ++kt)
                    bk[mt][kt] = load8(Kb + (size_t)(k0 + mt * 16 + lr) * D + kt * 32 + lq * 8);
        }
#pragma unroll 2
        for (int ks = w; ks <= qt; ks += 4) {
            const int k0 = ks * 32;
            // V for THIS step: issue early, consumed ~400 cyc later in PV
#pragma unroll
            for (int nt = 0; nt < 4; ++nt)
                bv[nt] = load8(Vb + (size_t)(nt * 16 + lr) * S + k0 + lq * 8);
            // S^T = K . Q^T   (A=K rows, B=Q rows)
            floatx4 sacc[2][2];
#pragma unroll
            for (int mt = 0; mt < 2; ++mt)
#pragma unroll
                for (int nt = 0; nt < 2; ++nt) sacc[mt][nt] = zero4;
#pragma unroll
            for (int mt = 0; mt < 2; ++mt)
#pragma unroll
                for (int nt = 0; nt < 2; ++nt)
#pragma unroll
                    for (int kt = 0; kt < 2; ++kt)
                        sacc[mt][nt] = __builtin_amdgcn_mfma_f32_16x16x32_bf16(
                            bk[mt][kt], bq[nt][kt], sacc[mt][nt], 0, 0, 0);
            // prefetch NEXT step's K (address-clamped; values unused if past end)
            const int k0n = ((ks + 4 <= qt) ? (ks + 4) : qt) * 32;
            short8 nk[2][2];
#pragma unroll
            for (int mt = 0; mt < 2; ++mt)
#pragma unroll
                for (int kt = 0; kt < 2; ++kt)
                    nk[mt][kt] = load8(Kb + (size_t)(k0n + mt * 16 + lr) * D + kt * 32 + lq * 8);
            // P = exp(s) (scale pre-folded into Q), causal mask, pack -> ds_write_b64
#pragma unroll
            for (int mt = 0; mt < 2; ++mt)
#pragma unroll
                for (int nt = 0; nt < 2; ++nt) {
                    const int qg = q0 + nt * 16 + lr;
                    const int kb = k0 + mt * 16 + lq * 4;
                    float p0 = (kb + 0 <= qg) ? __expf(sacc[mt][nt][0]) : 0.f;
                    float p1 = (kb + 1 <= qg) ? __expf(sacc[mt][nt][1]) : 0.f;
                    float p2 = (kb + 2 <= qg) ? __expf(sacc[mt][nt][2]) : 0.f;
                    float p3 = (kb + 3 <= qg) ? __expf(sacc[mt][nt][3]) : 0.f;
                    uint2 d;
                    d.x = pack_bf16(p0, p1);
                    d.y = pack_bf16(p2, p3);
                    *reinterpret_cast<uint2*>(lPw + (nt * 16 + lr) * 40 + mt * 16 + lq * 4) = d;
                }
            // in-wave LDS RAW fence (private region)
            asm volatile("s_waitcnt lgkmcnt(0)" ::: "memory");
            short8 ap[2];
#pragma unroll
            for (int mt = 0; mt < 2; ++mt)
                ap[mt] = load8(lPw + (mt * 16 + lr) * 40 + lq * 8);
#pragma unroll
            for (int mt = 0; mt < 2; ++mt)
                osum[mt] = __builtin_amdgcn_mfma_f32_16x16x32_bf16(ap[mt], ones, osum[mt], 0, 0, 0);
#pragma unroll
            for (int mt = 0; mt < 2; ++mt)
#pragma unroll
                for (int nt = 0; nt < 4; ++nt)
                    oacc[mt][nt] = __builtin_amdgcn_mfma_f32_16x16x32_bf16(
                        ap[mt], bv[nt], oacc[mt][nt], 0, 0, 0);
#pragma unroll
            for (int mt = 0; mt < 2; ++mt)
#pragma unroll
                for (int kt = 0; kt < 2; ++kt) bk[mt][kt] = nk[mt][kt];
        }
    }

    // ---- cross-wave reduce, two 32-col chunks (fp32, 18.4 KB) ----
    __syncthreads();  // everyone done with lP
    float* buf = reinterpret_cast<float*>(smem);  // [w][32][36]
    const int row = t >> 3, c4 = (t & 7) * 4;
    __hip_bfloat16* Ob = O + ((size_t)b * S) * D + h * 64;
    float inv = 0.f;
#pragma unroll
    for (int chunk = 0; chunk < 2; ++chunk) {
#pragma unroll
        for (int mt = 0; mt < 2; ++mt)
#pragma unroll
            for (int nt = 0; nt < 2; ++nt)
#pragma unroll
                for (int r = 0; r < 4; ++r)
                    buf[w * 1152 + (mt * 16 + lq * 4 + r) * 36 + nt * 16 + lr] =
                        oacc[mt][chunk * 2 + nt][r];
        if (chunk == 0 && lr == 0) {
#pragma unroll
            for (int mt = 0; mt < 2; ++mt)
#pragma unroll
                for (int r = 0; r < 4; ++r)
                    buf[w * 1152 + (mt * 16 + lq * 4 + r) * 36 + 32] = osum[mt][r];
        }
        __syncthreads();
        if (chunk == 0) {
            float Lt = buf[row * 36 + 32] + buf[1152 + row * 36 + 32] +
                       buf[2304 + row * 36 + 32] + buf[3456 + row * 36 + 32];
            inv = 1.f / Lt;
        }
        float4 a = {0.f, 0.f, 0.f, 0.f};
#pragma unroll
        for (int w2 = 0; w2 < 4; ++w2) {
            float4 v = *reinterpret_cast<const float4*>(buf + w2 * 1152 + row * 36 + c4);
            a.x += v.x; a.y += v.y; a.z += v.z; a.w += v.w;
        }
        uint2 d;
        d.x = pack_bf16(a.x * inv, a.y * inv);
        d.y = pack_bf16(a.z * inv, a.w * inv);
        *reinterpret_cast<uint2*>(Ob + (size_t)(q0 + row) * D + chunk * 32 + c4) = d;
        if (chunk == 0) __syncthreads();  // WAR before chunk-1 overwrites buf
    }
}

extern "C" void kernel_launch(void* const* d_in, const int* in_sizes, int n_in,
                              void* d_out, int out_size, void* d_ws, size_t ws_size,
                              hipStream_t stream) {
    const float* hs  = (const float*)d_in[0];  // [2,2048,1024]
    const float* wq  = (const float*)d_in[1];  // [1024,1024]
    const float* wk  = (const float*)d_in[2];
    const float* wv  = (const float*)d_in[3];
    const float* wo  = (const float*)d_in[4];
    const float* qkf = (const float*)d_in[5];  // scalar

    char* ws = (char*)d_ws;
    const size_t MB = 1024 * 1024;
    __hip_bfloat16* Xb  = (__hip_bfloat16*)(ws);            // 8 MB  [4096,1024]
    __hip_bfloat16* Wqb = (__hip_bfloat16*)(ws + 8 * MB);   // 2 MB each: Wq,Wk,Wv,Wo
    __hip_bfloat16* Wob = (__hip_bfloat16*)(ws + 14 * MB);
    __hip_bfloat16* Qb  = (__hip_bfloat16*)(ws + 16 * MB);  // 8 MB each, contiguous
    __hip_bfloat16* Kb  = (__hip_bfloat16*)(ws + 24 * MB);
    __hip_bfloat16* Vb  = (__hip_bfloat16*)(ws + 32 * MB);
    __hip_bfloat16* Vt  = (__hip_bfloat16*)(ws + 40 * MB);  // 8 MB [B,H,64,2048]
    __hip_bfloat16* Ab  = (__hip_bfloat16*)(ws + 48 * MB);  // 8 MB attn out

    cast_bf16<<<4096, 256, 0, stream>>>(hs, Xb, 1048576);
    cast4_bf16<<<dim3(1024, 4), 256, 0, stream>>>(wq, wk, wv, wo, Wqb);

    gemm_bt<__hip_bfloat16><<<dim3(32, 8, 3), 256, 0, stream>>>(
        Xb, Wqb, Qb, 1024, 1024, (size_t)1048576, (size_t)4194304);

    norm_heads<<<32768, 256, 0, stream>>>(Qb, Kb, 65536, qkf);
    transpose_v<<<dim3(32, 32), 256, 0, stream>>>(Vb, Vt);
    flash_attn<<<2048, 256, 0, stream>>>(Qb, Kb, Vt, Ab);

    gemm_bt<float><<<dim3(32, 8, 1), 256, 0, stream>>>(
        Ab, Wob, (float*)d_out, 1024, 1024, (size_t)0, (size_t)0);
}

// Round 4
// 197.262 us; speedup vs baseline: 1.5310x; 1.2101x over previous
//
#include <hip/hip_runtime.h>
#include <hip/hip_bf16.h>

typedef __attribute__((ext_vector_type(8))) short short8;
typedef __attribute__((ext_vector_type(4))) float floatx4;

union BF8 { short8 v; __hip_bfloat16 b[8]; };
union BF4U { ushort4 u; __hip_bfloat16 b[4]; };

__device__ __forceinline__ short8 load8(const __hip_bfloat16* p) {
    return *reinterpret_cast<const short8*>(p);
}

__device__ __forceinline__ void storeC(float* p, float v) { *p = v; }
__device__ __forceinline__ void storeC(__hip_bfloat16* p, float v) { *p = __float2bfloat16(v); }

// pack two fp32 -> two bf16 (round-half-up) in one dword: [lo]=a, [hi]=b
__device__ __forceinline__ unsigned pack_bf16(float a, float b) {
    unsigned ua = __float_as_uint(a) + 0x8000u;
    unsigned ub = __float_as_uint(b) + 0x8000u;
    return __builtin_amdgcn_perm(ub, ua, 0x07060302u);
}

// 2^x (v_exp_f32); scale/log2e pre-folded into Q
__device__ __forceinline__ float exp2_fast(float x) {
#if __has_builtin(__builtin_amdgcn_exp2f)
    return __builtin_amdgcn_exp2f(x);
#else
    return __expf(x * 0.6931471805599453f);
#endif
}

// async global->LDS, 16B per lane. LDS dest must be wave-uniform base + lane*16.
__device__ __forceinline__ void gload_lds16(const __hip_bfloat16* g, __hip_bfloat16* l) {
    __builtin_amdgcn_global_load_lds(
        (const __attribute__((address_space(1))) void*)g,
        (__attribute__((address_space(3))) void*)l, 16, 0, 0);
}

// -------- fp32 -> bf16 casts: y=0 hidden states (1M float4), y=1 the 4 weights ----
__global__ __launch_bounds__(256) void cast_all(const float* __restrict__ hs,
                                                const float* __restrict__ wq,
                                                const float* __restrict__ wk,
                                                const float* __restrict__ wv,
                                                const float* __restrict__ wo,
                                                __hip_bfloat16* __restrict__ Xb,
                                                __hip_bfloat16* __restrict__ Wb) {
    int i = blockIdx.x * 256 + threadIdx.x;  // grid.x = 4096 -> 1,048,576 float4
    const float* src;
    __hip_bfloat16* dst;
    if (blockIdx.y == 0) {
        src = hs; dst = Xb;
    } else {
        int m = i >> 18;
        src = (m == 0) ? wq : (m == 1) ? wk : (m == 2) ? wv : wo;
        src -= (size_t)m * 1048576;  // undo the global-index offset below
        dst = Wb;
    }
    float4 v = reinterpret_cast<const float4*>(src)[i];
    BF4U u;
    u.b[0] = __float2bfloat16(v.x);
    u.b[1] = __float2bfloat16(v.y);
    u.b[2] = __float2bfloat16(v.z);
    u.b[3] = __float2bfloat16(v.w);
    reinterpret_cast<ushort4*>(dst)[i] = u.u;
}

// ---------------- GEMM: C[M,N] = A[M,K] * B^T  (B given as [N,K] row-major) --------
// m97 structure; optional fused per-head L2 norm (z=0: Q, also scaled by
// qkf*log2e; z=1: K; z=2 / normz=0: none). Head = 64 cols = one wave's n-band.
template <typename OutT>
__global__ __launch_bounds__(256) void gemm_bt(const __hip_bfloat16* __restrict__ A,
                                               const __hip_bfloat16* __restrict__ B0,
                                               OutT* __restrict__ C0,
                                               int N, int Kd,
                                               size_t zsB, size_t zsC,
                                               int normz, const float* __restrict__ scale_p) {
    __shared__ __hip_bfloat16 lA[128 * 32];
    __shared__ __hip_bfloat16 lB[128 * 32];
    const __hip_bfloat16* B = B0 + zsB * blockIdx.z;
    OutT* C = C0 + zsC * blockIdx.z;
    const int t = threadIdx.x;
    const int m0 = blockIdx.x * 128, n0 = blockIdx.y * 128;
    const int w = t >> 6, l = t & 63;
    const int wr = (w >> 1) * 64, wc = (w & 1) * 64;
    const int lr = l & 15, lq = l >> 4;

    const floatx4 zero4 = {0.f, 0.f, 0.f, 0.f};
    floatx4 acc[4][4];
#pragma unroll
    for (int mt = 0; mt < 4; ++mt)
#pragma unroll
        for (int nt = 0; nt < 4; ++nt) acc[mt][nt] = zero4;

    for (int k0 = 0; k0 < Kd; k0 += 32) {
#pragma unroll
        for (int i = 0; i < 2; ++i) {
            int flat = t + i * 256;
            int row = flat >> 2, ch = flat & 3;
            gload_lds16(A + (size_t)(m0 + row) * Kd + k0 + ch * 8, lA + flat * 8);
            gload_lds16(B + (size_t)(n0 + row) * Kd + k0 + ch * 8, lB + flat * 8);
        }
        __syncthreads();
        short8 af[4], bfr[4];
#pragma unroll
        for (int mt = 0; mt < 4; ++mt)
            af[mt] = load8(lA + (wr + mt * 16 + lr) * 32 + lq * 8);
#pragma unroll
        for (int nt = 0; nt < 4; ++nt)
            bfr[nt] = load8(lB + (wc + nt * 16 + lr) * 32 + lq * 8);
#pragma unroll
        for (int mt = 0; mt < 4; ++mt)
#pragma unroll
            for (int nt = 0; nt < 4; ++nt)
                acc[mt][nt] = __builtin_amdgcn_mfma_f32_16x16x32_bf16(
                    af[mt], bfr[nt], acc[mt][nt], 0, 0, 0);
        __syncthreads();
    }

    if (normz && blockIdx.z < 2) {
        // row's head-cols {wc+lr, +16, +32, +48} live in the 4 nt regs; the 16
        // lr-lanes of a lq-quad cover the full 64-col head -> 4 xor-shuffles.
        const float fac = (blockIdx.z == 0) ? (*scale_p * 1.44269504f) : 1.0f;
#pragma unroll
        for (int mt = 0; mt < 4; ++mt)
#pragma unroll
            for (int r = 0; r < 4; ++r) {
                float ss = 0.f;
#pragma unroll
                for (int nt = 0; nt < 4; ++nt) {
                    float v = acc[mt][nt][r];
                    ss += v * v;
                }
                ss += __shfl_xor(ss, 1, 64);
                ss += __shfl_xor(ss, 2, 64);
                ss += __shfl_xor(ss, 4, 64);
                ss += __shfl_xor(ss, 8, 64);
                float inv = fac / (sqrtf(ss) + 1e-6f);
#pragma unroll
                for (int nt = 0; nt < 4; ++nt) acc[mt][nt][r] *= inv;
            }
    }

#pragma unroll
    for (int mt = 0; mt < 4; ++mt)
#pragma unroll
        for (int nt = 0; nt < 4; ++nt)
#pragma unroll
            for (int r = 0; r < 4; ++r) {
                int row = m0 + wr + mt * 16 + lq * 4 + r;
                int col = n0 + wc + nt * 16 + lr;
                storeC(C + (size_t)row * N + col, acc[mt][nt][r]);
            }
}

// ---------------- V [B,S,H,hd] -> Vt [B,H,hd,S] ----------------
__global__ __launch_bounds__(256) void transpose_v(const __hip_bfloat16* __restrict__ V,
                                                   __hip_bfloat16* __restrict__ Vt) {
    const int S = 2048, D = 1024;
    __shared__ __hip_bfloat16 tile[64][72];
    int t = threadIdx.x;
    int s0 = blockIdx.x * 64;
    int bh = blockIdx.y, b = bh >> 4, h = bh & 15;
    const __hip_bfloat16* src = V + ((size_t)b * S) * D + h * 64;
#pragma unroll
    for (int i = 0; i < 2; ++i) {
        int flat = t + i * 256;
        int sr = flat >> 3, ch = flat & 7;
        *reinterpret_cast<short8*>(&tile[sr][ch * 8]) =
            load8(src + (size_t)(s0 + sr) * D + ch * 8);
    }
    __syncthreads();
    __hip_bfloat16* dst = Vt + (size_t)bh * 64 * S;
#pragma unroll
    for (int i = 0; i < 2; ++i) {
        int flat = t + i * 256;
        int d = flat >> 3, sc = flat & 7;
        BF8 u;
#pragma unroll
        for (int j = 0; j < 8; ++j) u.b[j] = tile[sc * 8 + j][d];
        *reinterpret_cast<short8*>(dst + (size_t)d * S + s0 + sc * 8) = u.v;
    }
}

// ---------------- causal flash attention: 64 q-rows/block, k-split 4 waves -------
// S^T = K.Q^T (P exits with 4 k-consecutive values/lane -> pack + ds_write_b64).
// Causal mask peeled: only the last 2 k-steps of each q-block are masked.
// Q pre-scaled by qkf*log2e -> P = 2^s via v_exp_f32. Row sums in VALU.
__global__ __launch_bounds__(256) void flash_attn(const __hip_bfloat16* __restrict__ Q,
                                                  const __hip_bfloat16* __restrict__ K,
                                                  const __hip_bfloat16* __restrict__ Vt,
                                                  __hip_bfloat16* __restrict__ O) {
    const int S = 2048, D = 1024;
    // phase 1: 4 waves x (64 x 40) bf16 P-tiles = 20480 B (per-wave private)
    // phase 2: 4 waves x (64 x 20) fp32 partials = 20480 B (d in 4 chunks of 16)
    __shared__ __align__(16) char smem[20480];
    const int t = threadIdx.x;
    const int w = t >> 6, l = t & 63;
    const int lr = l & 15, lq = l >> 4;
    const int id = blockIdx.x, jj = id >> 3;
    const int bh = (id & 7) * 4 + (jj & 3);  // 4 heads per XCD (id%8 ~ XCD)
    const int jq = 31 - (jj >> 2);           // q-block (64 rows), long first
    const int b = bh >> 4, h = bh & 15;
    const int q0 = jq * 64;
    const __hip_bfloat16* Qb = Q + ((size_t)b * S) * D + h * 64;
    const __hip_bfloat16* Kb = K + ((size_t)b * S) * D + h * 64;
    const __hip_bfloat16* Vb = Vt + (size_t)bh * 64 * S;
    __hip_bfloat16* lPw = reinterpret_cast<__hip_bfloat16*>(smem) + w * (64 * 40);

    // Q as B-operand: 4 n-tiles (64 q-rows) x 2 k-chunks of head-dim
    short8 bq[4][2];
#pragma unroll
    for (int nt = 0; nt < 4; ++nt)
#pragma unroll
        for (int kt = 0; kt < 2; ++kt)
            bq[nt][kt] = load8(Qb + (size_t)(q0 + nt * 16 + lr) * D + kt * 32 + lq * 8);

    const floatx4 zero4 = {0.f, 0.f, 0.f, 0.f};
    floatx4 oacc[4][4];
    float lsum[4] = {0.f, 0.f, 0.f, 0.f};
#pragma unroll
    for (int mt = 0; mt < 4; ++mt)
#pragma unroll
        for (int nt = 0; nt < 4; ++nt) oacc[mt][nt] = zero4;

    auto body = [&](int k0, bool domask) {
        short8 bk[2][2], bv[4];
#pragma unroll
        for (int mt = 0; mt < 2; ++mt)
#pragma unroll
            for (int kt = 0; kt < 2; ++kt)
                bk[mt][kt] = load8(Kb + (size_t)(k0 + mt * 16 + lr) * D + kt * 32 + lq * 8);
#pragma unroll
        for (int nt = 0; nt < 4; ++nt)
            bv[nt] = load8(Vb + (size_t)(nt * 16 + lr) * S + k0 + lq * 8);
        floatx4 sacc[2][4];
#pragma unroll
        for (int mt = 0; mt < 2; ++mt)
#pragma unroll
            for (int nt = 0; nt < 4; ++nt) sacc[mt][nt] = zero4;
#pragma unroll
        for (int mt = 0; mt < 2; ++mt)
#pragma unroll
            for (int nt = 0; nt < 4; ++nt)
#pragma unroll
                for (int kt = 0; kt < 2; ++kt)
                    sacc[mt][nt] = __builtin_amdgcn_mfma_f32_16x16x32_bf16(
                        bk[mt][kt], bq[nt][kt], sacc[mt][nt], 0, 0, 0);
#pragma unroll
        for (int mt = 0; mt < 2; ++mt)
#pragma unroll
            for (int nt = 0; nt < 4; ++nt) {
                float p0 = exp2_fast(sacc[mt][nt][0]);
                float p1 = exp2_fast(sacc[mt][nt][1]);
                float p2 = exp2_fast(sacc[mt][nt][2]);
                float p3 = exp2_fast(sacc[mt][nt][3]);
                if (domask) {
                    const int qg = q0 + nt * 16 + lr;
                    const int kb = k0 + mt * 16 + lq * 4;
                    p0 = (kb + 0 <= qg) ? p0 : 0.f;
                    p1 = (kb + 1 <= qg) ? p1 : 0.f;
                    p2 = (kb + 2 <= qg) ? p2 : 0.f;
                    p3 = (kb + 3 <= qg) ? p3 : 0.f;
                }
                lsum[nt] += (p0 + p1) + (p2 + p3);
                uint2 d;
                d.x = pack_bf16(p0, p1);
                d.y = pack_bf16(p2, p3);
                *reinterpret_cast<uint2*>(lPw + (nt * 16 + lr) * 40 + mt * 16 + lq * 4) = d;
            }
        // in-wave LDS RAW fence (private region; no cross-wave barrier needed)
        asm volatile("s_waitcnt lgkmcnt(0)" ::: "memory");
        short8 ap[4];
#pragma unroll
        for (int mtq = 0; mtq < 4; ++mtq)
            ap[mtq] = load8(lPw + (mtq * 16 + lr) * 40 + lq * 8);
#pragma unroll
        for (int mtq = 0; mtq < 4; ++mtq)
#pragma unroll
            for (int ntd = 0; ntd < 4; ++ntd)
                oacc[mtq][ntd] = __builtin_amdgcn_mfma_f32_16x16x32_bf16(
                    ap[mtq], bv[ntd], oacc[mtq][ntd], 0, 0, 0);
    };

    int ks = w;
    for (; ks < 2 * jq; ks += 4) body(ks * 32, false);       // mask-free bulk
    for (; ks <= 2 * jq + 1; ks += 4) body(ks * 32, true);   // <=1 diagonal step/wave

    // reduce lsum over the 4 lq-quads (q index = nt*16+lr is lr-indexed)
#pragma unroll
    for (int nt = 0; nt < 4; ++nt) {
        float s = lsum[nt];
        s += __shfl_xor(s, 16, 64);
        s += __shfl_xor(s, 32, 64);
        lsum[nt] = s;
    }

    // ---- cross-wave reduce: d in 4 chunks of 16, buf[w][64][20] fp32 ----
    float* buf = reinterpret_cast<float*>(smem);
    const int row = t >> 2, c0 = (t & 3) * 4;
    __hip_bfloat16* Ob = O + ((size_t)b * S) * D + h * 64;
    float inv = 0.f;
#pragma unroll
    for (int chunk = 0; chunk < 4; ++chunk) {
#pragma unroll
        for (int mtq = 0; mtq < 4; ++mtq)
#pragma unroll
            for (int r = 0; r < 4; ++r)
                buf[w * 1280 + (mtq * 16 + lq * 4 + r) * 20 + lr] = oacc[mtq][chunk][r];
        if (chunk == 0 && lq == 0) {
#pragma unroll
            for (int nt = 0; nt < 4; ++nt)
                buf[w * 1280 + (nt * 16 + lr) * 20 + 16] = lsum[nt];
        }
        __syncthreads();
        if (chunk == 0) {
            float Lt = buf[row * 20 + 16] + buf[1280 + row * 20 + 16] +
                       buf[2560 + row * 20 + 16] + buf[3840 + row * 20 + 16];
            inv = 1.f / Lt;
        }
        float4 a = {0.f, 0.f, 0.f, 0.f};
#pragma unroll
        for (int w2 = 0; w2 < 4; ++w2) {
            float4 v = *reinterpret_cast<const float4*>(buf + w2 * 1280 + row * 20 + c0);
            a.x += v.x; a.y += v.y; a.z += v.z; a.w += v.w;
        }
        uint2 d;
        d.x = pack_bf16(a.x * inv, a.y * inv);
        d.y = pack_bf16(a.z * inv, a.w * inv);
        *reinterpret_cast<uint2*>(Ob + (size_t)(q0 + row) * D + chunk * 16 + c0) = d;
        if (chunk < 3) __syncthreads();  // WAR before next chunk's writes
    }
}

extern "C" void kernel_launch(void* const* d_in, const int* in_sizes, int n_in,
                              void* d_out, int out_size, void* d_ws, size_t ws_size,
                              hipStream_t stream) {
    const float* hs  = (const float*)d_in[0];  // [2,2048,1024]
    const float* wq  = (const float*)d_in[1];  // [1024,1024]
    const float* wk  = (const float*)d_in[2];
    const float* wv  = (const float*)d_in[3];
    const float* wo  = (const float*)d_in[4];
    const float* qkf = (const float*)d_in[5];  // scalar

    char* ws = (char*)d_ws;
    const size_t MB = 1024 * 1024;
    __hip_bfloat16* Xb  = (__hip_bfloat16*)(ws);            // 8 MB  [4096,1024]
    __hip_bfloat16* Wqb = (__hip_bfloat16*)(ws + 8 * MB);   // 2 MB each: Wq,Wk,Wv,Wo
    __hip_bfloat16* Wob = (__hip_bfloat16*)(ws + 14 * MB);
    __hip_bfloat16* Qb  = (__hip_bfloat16*)(ws + 16 * MB);  // 8 MB each, contiguous
    __hip_bfloat16* Vb  = (__hip_bfloat16*)(ws + 32 * MB);
    __hip_bfloat16* Vt  = (__hip_bfloat16*)(ws + 40 * MB);  // 8 MB [B,H,64,2048]
    __hip_bfloat16* Ab  = (__hip_bfloat16*)(ws + 48 * MB);  // 8 MB attn out
    __hip_bfloat16* Kb  = (__hip_bfloat16*)(ws + 24 * MB);

    cast_all<<<dim3(4096, 2), 256, 0, stream>>>(hs, wq, wk, wv, wo, Xb, Wqb);

    // QKV projections with fused hypersphere norm (Q also scaled by qkf*log2e)
    gemm_bt<__hip_bfloat16><<<dim3(32, 8, 3), 256, 0, stream>>>(
        Xb, Wqb, Qb, 1024, 1024, (size_t)1048576, (size_t)4194304, 1, qkf);

    transpose_v<<<dim3(32, 32), 256, 0, stream>>>(Vb, Vt);
    flash_attn<<<1024, 256, 0, stream>>>(Qb, Kb, Vt, Ab);

    gemm_bt<float><<<dim3(32, 8, 1), 256, 0, stream>>>(
        Ab, Wob, (float*)d_out, 1024, 1024, (size_t)0, (size_t)0, 0, qkf);
}